// Round 2
// baseline (597.072 us; speedup 1.0000x reference)
//
#include <hip/hip_runtime.h>
#include <hip/hip_cooperative_groups.h>
#include <math.h>

namespace cg = cooperative_groups;

// CIRNet: T=1048576 rows x 18 feats. Outputs concat: r_predicts[N], regs[N], dts[N], N=T-1.
// Single cooperative kernel: prep -> 3x(chunk-Newton + grid-wide affine scan) -> final.
// Chunk length 4 => one chunk per thread, dt/pp stay in registers across all iterations.
#define NSTEPS  1048575
#define FEAT    18
#define THREADS 1024
#define BLOCKS  256
#define TOT     (THREADS * BLOCKS)   // 262144 chunks of 4 steps
#define NITER   3

__device__ __forceinline__ void wave_scan_affine(float& A, float& B, int lane) {
    // inclusive scan of affine maps x->Ax+B in lane order; compose later o earlier
#pragma unroll
    for (int d = 1; d < 64; d <<= 1) {
        float pA = __shfl_up(A, d, 64);
        float pB = __shfl_up(B, d, 64);
        if (lane >= d) { B = fmaf(A, pB, B); A *= pA; }
    }
}

__global__ void __launch_bounds__(THREADS, 4) cir_all(
    const float* __restrict__ trace,
    const float* __restrict__ sW,
    const float* __restrict__ sb,
    const float* __restrict__ eW,
    const float* __restrict__ kp,
    const float* __restrict__ thp,
    float* __restrict__ out,
    float* __restrict__ dtw,
    float* __restrict__ ppw,
    float* __restrict__ gaggA,
    float* __restrict__ gaggB)
{
    cg::grid_group grid = cg::this_grid();
    __shared__ float wA[16], wB[16];
    __shared__ float gA[256], gB[256];

    const int tid  = threadIdx.x;
    const int lane = tid & 63;
    const int wid  = tid >> 6;
    const int c    = blockIdx.x * THREADS + tid;   // chunk id

    const float k  = kp[0];
    const float th = thp[0];
    const float r0 = trace[1];
    const float sbv = sb[0];
    float sw[8], ew[8];
#pragma unroll
    for (int j = 0; j < 8; ++j) { sw[j] = sW[j]; ew[j] = eW[j]; }

    // ---------------- phase 0: prep (coalesced grid-stride) ----------------
#pragma unroll
    for (int i = 0; i < 4; ++i) {
        int n = c + i * TOT;
        if (n < NSTEPS) {
            const float2* r2 = (const float2*)(trace + (long)n * FEAT);
            float2 e0 = r2[0], e1 = r2[1], e2 = r2[2], e3 = r2[3], e4 = r2[4];
            float2 e5 = r2[5], e6 = r2[6], e7 = r2[7], e8 = r2[8];
            float tn1 = trace[(long)(n + 1) * FEAT];
            float d = tn1 - e0.x;
            float sig = sbv;
            sig = fmaf(e1.x, sw[0], sig); sig = fmaf(e1.y, sw[1], sig);
            sig = fmaf(e2.x, sw[2], sig); sig = fmaf(e2.y, sw[3], sig);
            sig = fmaf(e3.x, sw[4], sig); sig = fmaf(e3.y, sw[5], sig);
            sig = fmaf(e4.x, sw[6], sig); sig = fmaf(e4.y, sw[7], sig);
            float ep = 0.f;
            ep = fmaf(e5.x, ew[0], ep); ep = fmaf(e5.y, ew[1], ep);
            ep = fmaf(e6.x, ew[2], ep); ep = fmaf(e6.y, ew[3], ep);
            ep = fmaf(e7.x, ew[4], ep); ep = fmaf(e7.y, ew[5], ep);
            ep = fmaf(e8.x, ew[6], ep); ep = fmaf(e8.y, ew[7], ep);
            dtw[n] = d;
            ppw[n] = sig * ep;
            out[NSTEPS + n]     = fmaf(-sig, sig, 2.f * k * th);  // regs
            out[2 * NSTEPS + n] = d;                              // dts
        }
    }
    __threadfence();
    grid.sync();

    // ---------------- load this thread's 4 steps into registers ----------------
    const int nb = 4 * c;
    float4 dv = *(const float4*)(dtw + nb);
    float4 pv = *(const float4*)(ppw + nb);
    const bool v3 = (nb + 3) < NSTEPS;   // only last thread's 4th step is invalid

    float s = r0;              // chunk start (Newton iterate), init = r0 everywhere
    float Ate = 1.f, Bte = 0.f;

    // ---------------- Newton iterations ----------------
    for (int iter = 0; iter < NITER; ++iter) {
        // forward 4 steps from s with derivative product
        float E = s, P = 1.f;
#define GSTEP(dd, pj, valid) if (valid) { \
            float u   = E * (dd); \
            float au  = fabsf(u); \
            float qs  = sqrtf(au); \
            float ode = fmaf(k * (th - E), (dd), E); \
            float a   = fmaf(-k, (dd), 1.f); \
            float inv = (au > 1e-30f) ? rsqrtf(au) : 0.f; \
            float grad = fmaf((pj), 0.5f * (dd) * copysignf(inv, E), a); \
            E = fmaf((pj), qs, ode); \
            P *= grad; }
        GSTEP(dv.x, pv.x, true)
        GSTEP(dv.y, pv.y, true)
        GSTEP(dv.z, pv.z, true)
        GSTEP(dv.w, pv.w, v3)
#undef GSTEP
        float A = P;
        float B = fmaf(-P, s, E);

        // wave inclusive scan
        float iA = A, iB = B;
        wave_scan_affine(iA, iB, lane);
        if (lane == 63) { wA[wid] = iA; wB[wid] = iB; }
        __syncthreads();
        if (wid == 0) {
            float aA = (lane < 16) ? wA[lane] : 1.f;
            float aB = (lane < 16) ? wB[lane] : 0.f;
            wave_scan_affine(aA, aB, lane);
            if (lane < 16) { wA[lane] = aA; wB[lane] = aB; }
        }
        __syncthreads();
        float weA = 1.f, weB = 0.f;
        if (wid > 0) { weA = wA[wid - 1]; weB = wB[wid - 1]; }
        // thread-exclusive within wave
        float eA = __shfl_up(iA, 1, 64), eB = __shfl_up(iB, 1, 64);
        if (lane == 0) { eA = 1.f; eB = 0.f; }
        // thread-exclusive within block = exclLocal o waveExcl
        Ate = eA * weA;
        Bte = fmaf(eA, weB, eB);

        // block aggregate (inclusive over 16 waves) -> global, ping-pong buffer
        const int buf = (iter & 1) * 256;
        if (tid == 0) { gaggA[buf + blockIdx.x] = wA[15]; gaggB[buf + blockIdx.x] = wB[15]; }
        __threadfence();
        grid.sync();

        // every block redundantly scans the 256 block aggregates
        if (tid < 256) { gA[tid] = gaggA[buf + tid]; gB[tid] = gaggB[buf + tid]; }
        __syncthreads();
        for (int d = 1; d < 256; d <<= 1) {
            float pA = 1.f, pB = 0.f;
            bool act = (tid < 256) && (tid >= d);
            if (act) { pA = gA[tid - d]; pB = gB[tid - d]; }
            __syncthreads();
            if (act) { gB[tid] = fmaf(gA[tid], pB, gB[tid]); gA[tid] *= pA; }
            __syncthreads();
        }
        float beA = 1.f, beB = 0.f;
        if (blockIdx.x > 0) { beA = gA[blockIdx.x - 1]; beB = gB[blockIdx.x - 1]; }
        // full exclusive prefix for this chunk = threadExcl o blockExcl
        float FA = Ate * beA;
        float FB = fmaf(Ate, beB, Bte);
        s = fmaf(FA, r0, FB);
        // gA/gB reads done before next grid.sync; wA/wB rewritten only after it -> safe
    }

    // ---------------- final forward, write r_predicts ----------------
    {
        float r = s;
        float4 ov;
#define FSTEP(dd, pj) { \
            float qs = sqrtf(fabsf(r * (dd))); \
            r = fmaf((pj), qs, fmaf(k * (th - r), (dd), r)); }
        FSTEP(dv.x, pv.x) ov.x = r;
        FSTEP(dv.y, pv.y) ov.y = r;
        FSTEP(dv.z, pv.z) ov.z = r;
        FSTEP(dv.w, pv.w) ov.w = r;
#undef FSTEP
        if (nb + 4 <= NSTEPS) {
            *(float4*)(out + nb) = ov;
        } else {
            out[nb + 0] = ov.x;
            out[nb + 1] = ov.y;
            out[nb + 2] = ov.z;   // nb+3 == NSTEPS-? last thread writes 3
        }
    }
}

extern "C" void kernel_launch(void* const* d_in, const int* in_sizes, int n_in,
                              void* d_out, int out_size, void* d_ws, size_t ws_size,
                              hipStream_t stream)
{
    const float* trace = (const float*)d_in[0];
    const float* sW    = (const float*)d_in[1];
    const float* sb    = (const float*)d_in[2];
    const float* eW    = (const float*)d_in[3];
    const float* kp    = (const float*)d_in[4];
    const float* thp   = (const float*)d_in[5];
    float* out = (float*)d_out;

    float* w     = (float*)d_ws;
    float* dtw   = w;                    // 1048576 floats
    float* ppw   = w + 1048576;          // 1048576 floats
    float* gaggA = w + 2 * 1048576;      // 2*256 floats (ping-pong)
    float* gaggB = gaggA + 512;          // 2*256 floats

    void* args[] = { (void*)&trace, (void*)&sW, (void*)&sb, (void*)&eW,
                     (void*)&kp, (void*)&thp, (void*)&out,
                     (void*)&dtw, (void*)&ppw, (void*)&gaggA, (void*)&gaggB };
    hipLaunchCooperativeKernel((const void*)cir_all, dim3(BLOCKS), dim3(THREADS),
                               args, 0, stream);
}

// Round 3
// 157.668 us; speedup vs baseline: 3.7869x; 3.7869x over previous
//
#include <hip/hip_runtime.h>
#include <math.h>

// CIRNet: T=1048576 rows x 18 feats. Outputs concat: r_predicts[N], regs[N], dts[N], N=T-1.
// Multi-kernel chunked-Newton scan. Per-step map: r' = a*r + b + c*sqrt(|r|),
//   a = 1 - k*d, b = k*th*d, c = sig*eps*sqrt(d)  (precomputed (d,c) in prep;
//   pad steps stored as (0,0) -> exact identity, no bounds checks in hot loops).
#define NSTEPS  1048575
#define NPAD    1048576
#define FEAT    18
#define CLEN    64
#define CHUNKS  (NPAD / CLEN)      // 16384
#define SCANT   1024
#define PERT    (CHUNKS / SCANT)   // 16 chunks per scan thread

// ---------------- K1: per-step coefficients + regs/dts ----------------
__global__ void prep_kernel(const float* __restrict__ trace,
                            const float* __restrict__ sW, const float* __restrict__ sb,
                            const float* __restrict__ eW, const float* __restrict__ kp,
                            const float* __restrict__ thp,
                            float2* __restrict__ dc, float* __restrict__ out)
{
    int n = blockIdx.x * blockDim.x + threadIdx.x;   // grid covers NPAD exactly
    if (n >= NSTEPS) { dc[n] = make_float2(0.f, 0.f); return; }
    const float* row = trace + (long)n * FEAT;
    float d = row[FEAT] - row[0];
    float sig = sb[0];
#pragma unroll
    for (int j = 0; j < 8; ++j) sig = fmaf(row[2 + j], sW[j], sig);
    float ep = 0.f;
#pragma unroll
    for (int j = 0; j < 8; ++j) ep = fmaf(row[10 + j], eW[j], ep);
    float k = kp[0], th = thp[0];
    dc[n] = make_float2(d, sig * ep * sqrtf(fabsf(d)));
    out[NSTEPS + n]     = fmaf(-sig, sig, 2.f * k * th);  // regs
    out[2 * NSTEPS + n] = d;                              // dts
}

// one step + derivative-product update
#define GSTEP(dd, cc) { \
    float a   = fmaf(-k, (dd), 1.f); \
    float b   = kth * (dd); \
    float ar  = fabsf(r); \
    float sq  = sqrtf(ar); \
    float inv = (ar > 1e-30f) ? rsqrtf(ar) : 0.f; \
    float g   = fmaf(0.5f * (cc), copysignf(inv, r), a); \
    r = fmaf((cc), sq, fmaf(a, r, b)); \
    P *= g; }

// ---------------- K2: chunk forward pass, writes affine (A,B) ----------------
__global__ void chunk_pass(const float2* __restrict__ dc,
                           const float* __restrict__ starts, int first,
                           const float* __restrict__ trace,
                           const float* __restrict__ kp, const float* __restrict__ thp,
                           float2* __restrict__ ab)
{
    int c = blockIdx.x * blockDim.x + threadIdx.x;
    float k = kp[0], th = thp[0];
    float kth = k * th;
    float s;
    if (first) {
        // ODE closed-form seed: th + (r0-th)*exp(-k*(t_c - t_0))
        float r0 = trace[1];
        float tc = trace[(long)c * CLEN * FEAT];
        float t0 = trace[0];
        s = th + (r0 - th) * __expf(-k * (tc - t0));
    } else {
        s = starts[c];
    }
    const float4* q = (const float4*)(dc + (long)c * CLEN);
    float4 buf[32];
#pragma unroll
    for (int i = 0; i < 32; ++i) buf[i] = q[i];
    float r = s, P = 1.f;
#pragma unroll
    for (int i = 0; i < 32; ++i) {
        GSTEP(buf[i].x, buf[i].y)
        GSTEP(buf[i].z, buf[i].w)
    }
    ab[c] = make_float2(P, fmaf(-P, s, r));   // (A, B): x -> A*x + B
}

// ---------------- K3: scan 16384 affine maps in one block ----------------
__device__ __forceinline__ void wave_scan_affine(float& A, float& B, int lane) {
#pragma unroll
    for (int d = 1; d < 64; d <<= 1) {
        float pA = __shfl_up(A, d, 64);
        float pB = __shfl_up(B, d, 64);
        if (lane >= d) { B = fmaf(A, pB, B); A *= pA; }
    }
}

__global__ void __launch_bounds__(SCANT) correct_scan(const float2* __restrict__ ab,
                                                      const float* __restrict__ trace,
                                                      float* __restrict__ s_new)
{
    __shared__ float wAs[16], wBs[16];
    int t = threadIdx.x, lane = t & 63, wid = t >> 6;
    const float4* q = (const float4*)(ab + t * PERT);
    float A[PERT], B[PERT];
#pragma unroll
    for (int i = 0; i < PERT / 2; ++i) {
        float4 v = q[i];
        A[2 * i] = v.x; B[2 * i] = v.y;
        A[2 * i + 1] = v.z; B[2 * i + 1] = v.w;
    }
    float aggA = 1.f, aggB = 0.f;
#pragma unroll
    for (int j = 0; j < PERT; ++j) { aggB = fmaf(A[j], aggB, B[j]); aggA *= A[j]; }
    float iA = aggA, iB = aggB;
    wave_scan_affine(iA, iB, lane);
    if (lane == 63) { wAs[wid] = iA; wBs[wid] = iB; }
    __syncthreads();
    if (wid == 0) {
        float aA = (lane < 16) ? wAs[lane] : 1.f;
        float aB = (lane < 16) ? wBs[lane] : 0.f;
        wave_scan_affine(aA, aB, lane);
        if (lane < 16) { wAs[lane] = aA; wBs[lane] = aB; }
    }
    __syncthreads();
    float weA = 1.f, weB = 0.f;
    if (wid > 0) { weA = wAs[wid - 1]; weB = wBs[wid - 1]; }
    float eA = __shfl_up(iA, 1, 64), eB = __shfl_up(iB, 1, 64);
    if (lane == 0) { eA = 1.f; eB = 0.f; }
    float xA = eA * weA;                 // thread-exclusive prefix map
    float xB = fmaf(eA, weB, eB);
    float r0 = trace[1];
    float x = fmaf(xA, r0, xB);
#pragma unroll
    for (int i = 0; i < PERT / 4; ++i) {
        float4 ov;
        ov.x = x; x = fmaf(A[4 * i + 0], x, B[4 * i + 0]);
        ov.y = x; x = fmaf(A[4 * i + 1], x, B[4 * i + 1]);
        ov.z = x; x = fmaf(A[4 * i + 2], x, B[4 * i + 2]);
        ov.w = x; x = fmaf(A[4 * i + 3], x, B[4 * i + 3]);
        ((float4*)(s_new + t * PERT))[i] = ov;
    }
}

// ---------------- K4: final forward pass writing r_predicts ----------------
#define FSTEP(dd, cc) { \
    float a = fmaf(-k, (dd), 1.f); \
    float b = kth * (dd); \
    r = fmaf((cc), sqrtf(fabsf(r)), fmaf(a, r, b)); }

__global__ void final_pass(const float2* __restrict__ dc,
                           const float* __restrict__ starts,
                           const float* __restrict__ kp, const float* __restrict__ thp,
                           float* __restrict__ out)
{
    int c = blockIdx.x * blockDim.x + threadIdx.x;
    float k = kp[0], th = thp[0];
    float kth = k * th;
    float r = starts[c];
    const float4* q = (const float4*)(dc + (long)c * CLEN);
    float4 buf[32];
#pragma unroll
    for (int i = 0; i < 32; ++i) buf[i] = q[i];
    int nb = c * CLEN;
#pragma unroll
    for (int i = 0; i < 16; ++i) {   // 4 steps -> one float4 store
        float4 ov;
        FSTEP(buf[2 * i].x, buf[2 * i].y)         ov.x = r;
        FSTEP(buf[2 * i].z, buf[2 * i].w)         ov.y = r;
        FSTEP(buf[2 * i + 1].x, buf[2 * i + 1].y) ov.z = r;
        FSTEP(buf[2 * i + 1].z, buf[2 * i + 1].w) ov.w = r;
        int n0 = nb + 4 * i;
        if (n0 + 4 <= NSTEPS) {
            *(float4*)(out + n0) = ov;
        } else {                      // only the very last group of last thread
            if (n0 + 0 < NSTEPS) out[n0 + 0] = ov.x;
            if (n0 + 1 < NSTEPS) out[n0 + 1] = ov.y;
            if (n0 + 2 < NSTEPS) out[n0 + 2] = ov.z;
        }
    }
}

extern "C" void kernel_launch(void* const* d_in, const int* in_sizes, int n_in,
                              void* d_out, int out_size, void* d_ws, size_t ws_size,
                              hipStream_t stream)
{
    const float* trace = (const float*)d_in[0];
    const float* sW    = (const float*)d_in[1];
    const float* sb    = (const float*)d_in[2];
    const float* eW    = (const float*)d_in[3];
    const float* kp    = (const float*)d_in[4];
    const float* thp   = (const float*)d_in[5];
    float* out = (float*)d_out;

    float*  w     = (float*)d_ws;
    float2* dc    = (float2*)w;                     // NPAD float2 = 8 MB
    float2* ab    = (float2*)(w + 2 * NPAD);        // CHUNKS float2 = 128 KB
    float*  s_new = w + 2 * NPAD + 2 * CHUNKS;      // CHUNKS floats

    prep_kernel<<<NPAD / 256, 256, 0, stream>>>(trace, sW, sb, eW, kp, thp, dc, out);

    // Newton iteration 1 (ODE closed-form seed)
    chunk_pass<<<CHUNKS / 256, 256, 0, stream>>>(dc, s_new, 1, trace, kp, thp, ab);
    correct_scan<<<1, SCANT, 0, stream>>>(ab, trace, s_new);
    // Newton iteration 2
    chunk_pass<<<CHUNKS / 256, 256, 0, stream>>>(dc, s_new, 0, trace, kp, thp, ab);
    correct_scan<<<1, SCANT, 0, stream>>>(ab, trace, s_new);

    final_pass<<<CHUNKS / 256, 256, 0, stream>>>(dc, s_new, kp, thp, out);
}

// Round 4
// 142.612 us; speedup vs baseline: 4.1867x; 1.1056x over previous
//
#include <hip/hip_runtime.h>
#include <math.h>

// CIRNet: T=1048576 rows x 18 feats. Outputs concat: r_predicts[N], regs[N], dts[N], N=T-1.
// Chunked-Newton scan, SINGLE Newton iteration (ODE closed-form seed):
//   prep -> chunk_pass (affine A,B per chunk) -> scan (corrected starts) -> final.
// Per-step map: r' = a*r + b + c*sqrt(|r|), a = 1-k*d, b = k*th*d, c = sig*eps*sqrt(d).
// Pad steps stored as (0,0) -> exact identity, no bounds checks in hot loops.
#define NSTEPS  1048575
#define NPAD    1048576
#define FEAT    18
#define CLEN    64
#define CHUNKS  (NPAD / CLEN)      // 16384
#define SCANT   1024
#define PERT    (CHUNKS / SCANT)   // 16 chunks per scan thread

// ---------------- K1: per-step coefficients + regs/dts ----------------
__global__ void prep_kernel(const float* __restrict__ trace,
                            const float* __restrict__ sW, const float* __restrict__ sb,
                            const float* __restrict__ eW, const float* __restrict__ kp,
                            const float* __restrict__ thp,
                            float2* __restrict__ dc, float* __restrict__ out)
{
    int n = blockIdx.x * blockDim.x + threadIdx.x;   // grid covers NPAD exactly
    if (n >= NSTEPS) { dc[n] = make_float2(0.f, 0.f); return; }
    const float* row = trace + (long)n * FEAT;
    float d = row[FEAT] - row[0];
    float sig = sb[0];
#pragma unroll
    for (int j = 0; j < 8; ++j) sig = fmaf(row[2 + j], sW[j], sig);
    float ep = 0.f;
#pragma unroll
    for (int j = 0; j < 8; ++j) ep = fmaf(row[10 + j], eW[j], ep);
    float k = kp[0], th = thp[0];
    dc[n] = make_float2(d, sig * ep * sqrtf(fabsf(d)));
    out[NSTEPS + n]     = fmaf(-sig, sig, 2.f * k * th);  // regs
    out[2 * NSTEPS + n] = d;                              // dts
}

// one step + derivative-product update
#define GSTEP(dd, cc) { \
    float a   = fmaf(-k, (dd), 1.f); \
    float b   = kth * (dd); \
    float ar  = fabsf(r); \
    float sq  = sqrtf(ar); \
    float inv = (ar > 1e-30f) ? rsqrtf(ar) : 0.f; \
    float g   = fmaf(0.5f * (cc), copysignf(inv, r), a); \
    r = fmaf((cc), sq, fmaf(a, r, b)); \
    P *= g; }

// ---------------- K2: chunk forward pass (ODE seed), writes affine (A,B) ----------------
__global__ void chunk_pass(const float2* __restrict__ dc,
                           const float* __restrict__ trace,
                           const float* __restrict__ kp, const float* __restrict__ thp,
                           float2* __restrict__ ab)
{
    int c = blockIdx.x * blockDim.x + threadIdx.x;
    float k = kp[0], th = thp[0];
    float kth = k * th;
    // ODE closed-form seed: th + (r0-th)*exp(-k*(t_c - t_0))
    float r0 = trace[1];
    float tc = trace[(long)c * CLEN * FEAT];
    float t0 = trace[0];
    float s = th + (r0 - th) * __expf(-k * (tc - t0));
    const float4* q = (const float4*)(dc + (long)c * CLEN);
    float4 buf[32];
#pragma unroll
    for (int i = 0; i < 32; ++i) buf[i] = q[i];
    float r = s, P = 1.f;
#pragma unroll
    for (int i = 0; i < 32; ++i) {
        GSTEP(buf[i].x, buf[i].y)
        GSTEP(buf[i].z, buf[i].w)
    }
    ab[c] = make_float2(P, fmaf(-P, s, r));   // (A, B): x -> A*x + B
}

// ---------------- K3: scan 16384 affine maps in one block -> corrected starts ----------------
__device__ __forceinline__ void wave_scan_affine(float& A, float& B, int lane) {
#pragma unroll
    for (int d = 1; d < 64; d <<= 1) {
        float pA = __shfl_up(A, d, 64);
        float pB = __shfl_up(B, d, 64);
        if (lane >= d) { B = fmaf(A, pB, B); A *= pA; }
    }
}

__global__ void __launch_bounds__(SCANT) correct_scan(const float2* __restrict__ ab,
                                                      const float* __restrict__ trace,
                                                      float* __restrict__ s_new)
{
    __shared__ float wAs[16], wBs[16];
    int t = threadIdx.x, lane = t & 63, wid = t >> 6;
    const float4* q = (const float4*)(ab + t * PERT);
    float A[PERT], B[PERT];
#pragma unroll
    for (int i = 0; i < PERT / 2; ++i) {
        float4 v = q[i];
        A[2 * i] = v.x; B[2 * i] = v.y;
        A[2 * i + 1] = v.z; B[2 * i + 1] = v.w;
    }
    float aggA = 1.f, aggB = 0.f;
#pragma unroll
    for (int j = 0; j < PERT; ++j) { aggB = fmaf(A[j], aggB, B[j]); aggA *= A[j]; }
    float iA = aggA, iB = aggB;
    wave_scan_affine(iA, iB, lane);
    if (lane == 63) { wAs[wid] = iA; wBs[wid] = iB; }
    __syncthreads();
    if (wid == 0) {
        float aA = (lane < 16) ? wAs[lane] : 1.f;
        float aB = (lane < 16) ? wBs[lane] : 0.f;
        wave_scan_affine(aA, aB, lane);
        if (lane < 16) { wAs[lane] = aA; wBs[lane] = aB; }
    }
    __syncthreads();
    float weA = 1.f, weB = 0.f;
    if (wid > 0) { weA = wAs[wid - 1]; weB = wBs[wid - 1]; }
    float eA = __shfl_up(iA, 1, 64), eB = __shfl_up(iB, 1, 64);
    if (lane == 0) { eA = 1.f; eB = 0.f; }
    float xA = eA * weA;                 // thread-exclusive prefix map
    float xB = fmaf(eA, weB, eB);
    float r0 = trace[1];
    float x = fmaf(xA, r0, xB);
#pragma unroll
    for (int i = 0; i < PERT / 4; ++i) {
        float4 ov;
        ov.x = x; x = fmaf(A[4 * i + 0], x, B[4 * i + 0]);
        ov.y = x; x = fmaf(A[4 * i + 1], x, B[4 * i + 1]);
        ov.z = x; x = fmaf(A[4 * i + 2], x, B[4 * i + 2]);
        ov.w = x; x = fmaf(A[4 * i + 3], x, B[4 * i + 3]);
        ((float4*)(s_new + t * PERT))[i] = ov;
    }
}

// ---------------- K4: final forward pass writing r_predicts ----------------
#define FSTEP(dd, cc) { \
    float a = fmaf(-k, (dd), 1.f); \
    float b = kth * (dd); \
    r = fmaf((cc), sqrtf(fabsf(r)), fmaf(a, r, b)); }

__global__ void final_pass(const float2* __restrict__ dc,
                           const float* __restrict__ starts,
                           const float* __restrict__ kp, const float* __restrict__ thp,
                           float* __restrict__ out)
{
    int c = blockIdx.x * blockDim.x + threadIdx.x;
    float r = starts[c];
    float k = kp[0], th = thp[0];
    float kth = k * th;
    const float4* q = (const float4*)(dc + (long)c * CLEN);
    float4 buf[32];
#pragma unroll
    for (int i = 0; i < 32; ++i) buf[i] = q[i];
    int nb = c * CLEN;
#pragma unroll
    for (int i = 0; i < 16; ++i) {   // 4 steps -> one float4 store
        float4 ov;
        FSTEP(buf[2 * i].x, buf[2 * i].y)         ov.x = r;
        FSTEP(buf[2 * i].z, buf[2 * i].w)         ov.y = r;
        FSTEP(buf[2 * i + 1].x, buf[2 * i + 1].y) ov.z = r;
        FSTEP(buf[2 * i + 1].z, buf[2 * i + 1].w) ov.w = r;
        int n0 = nb + 4 * i;
        if (n0 + 4 <= NSTEPS) {
            *(float4*)(out + n0) = ov;
        } else {                      // only the very last group of last thread
            if (n0 + 0 < NSTEPS) out[n0 + 0] = ov.x;
            if (n0 + 1 < NSTEPS) out[n0 + 1] = ov.y;
            if (n0 + 2 < NSTEPS) out[n0 + 2] = ov.z;
        }
    }
}

extern "C" void kernel_launch(void* const* d_in, const int* in_sizes, int n_in,
                              void* d_out, int out_size, void* d_ws, size_t ws_size,
                              hipStream_t stream)
{
    const float* trace = (const float*)d_in[0];
    const float* sW    = (const float*)d_in[1];
    const float* sb    = (const float*)d_in[2];
    const float* eW    = (const float*)d_in[3];
    const float* kp    = (const float*)d_in[4];
    const float* thp   = (const float*)d_in[5];
    float* out = (float*)d_out;

    float*  w     = (float*)d_ws;
    float2* dc    = (float2*)w;                     // NPAD float2 = 8 MB
    float2* ab    = (float2*)(w + 2 * NPAD);        // CHUNKS float2 = 128 KB
    float*  s_new = w + 2 * NPAD + 2 * CHUNKS;      // CHUNKS floats

    prep_kernel<<<NPAD / 256, 256, 0, stream>>>(trace, sW, sb, eW, kp, thp, dc, out);
    // single Newton iteration (ODE closed-form seed)
    chunk_pass<<<CHUNKS / 256, 256, 0, stream>>>(dc, trace, kp, thp, ab);
    correct_scan<<<1, SCANT, 0, stream>>>(ab, trace, s_new);
    final_pass<<<CHUNKS / 256, 256, 0, stream>>>(dc, s_new, kp, thp, out);
}

// Round 5
// 128.745 us; speedup vs baseline: 4.6376x; 1.1077x over previous
//
#include <hip/hip_runtime.h>
#include <math.h>

// CIRNet: T=1048576 rows x 18 feats. Outputs concat: r_predicts[N], regs[N], dts[N], N=T-1.
// 2 launches:
//  K1 prep: per-step (d, c=sig*eps*sqrt(d)) coeffs, regs/dts outputs, per-chunk ODE seeds,
//           zeroes barrier counter.
//  K2 fused: per-thread 4-step Newton-linearized affine map -> block scan -> device-scope
//           spin barrier over 256 co-resident blocks -> global scan -> replay + store.
// Per-step map: r' = a*r + b + c*sqrt(|r|), a = 1-k*d, b = k*th*d.
// Pad step (n=NSTEPS) stored as (0,0) -> exact identity.
#define NSTEPS  1048575
#define NPAD    1048576
#define FEAT    18
#define CLEN    4
#define CHUNKS  (NPAD / CLEN)      // 262144
#define K2B     256                // blocks (<= 256 CUs -> co-resident)
#define K2T     1024               // threads

// ---------------- K1: coefficients + regs/dts + seeds ----------------
__global__ void prep_kernel(const float* __restrict__ trace,
                            const float* __restrict__ sW, const float* __restrict__ sb,
                            const float* __restrict__ eW, const float* __restrict__ kp,
                            const float* __restrict__ thp,
                            float2* __restrict__ dc, float* __restrict__ seeds,
                            float* __restrict__ out, unsigned int* __restrict__ cnt)
{
    int n = blockIdx.x * blockDim.x + threadIdx.x;   // grid covers NPAD exactly
    if (n == 0) *cnt = 0;                            // ws re-poisoned before every launch
    if (n >= NSTEPS) { dc[n] = make_float2(0.f, 0.f); return; }
    const float2* r2 = (const float2*)(trace + (long)n * FEAT);
    float2 e0 = r2[0], e1 = r2[1], e2 = r2[2], e3 = r2[3], e4 = r2[4];
    float2 e5 = r2[5], e6 = r2[6], e7 = r2[7], e8 = r2[8];
    float tn1 = trace[(long)(n + 1) * FEAT];
    float d = tn1 - e0.x;
    float sig = sb[0];
    sig = fmaf(e1.x, sW[0], sig); sig = fmaf(e1.y, sW[1], sig);
    sig = fmaf(e2.x, sW[2], sig); sig = fmaf(e2.y, sW[3], sig);
    sig = fmaf(e3.x, sW[4], sig); sig = fmaf(e3.y, sW[5], sig);
    sig = fmaf(e4.x, sW[6], sig); sig = fmaf(e4.y, sW[7], sig);
    float ep = 0.f;
    ep = fmaf(e5.x, eW[0], ep); ep = fmaf(e5.y, eW[1], ep);
    ep = fmaf(e6.x, eW[2], ep); ep = fmaf(e6.y, eW[3], ep);
    ep = fmaf(e7.x, eW[4], ep); ep = fmaf(e7.y, eW[5], ep);
    ep = fmaf(e8.x, eW[6], ep); ep = fmaf(e8.y, eW[7], ep);
    float k = kp[0], th = thp[0];
    dc[n] = make_float2(d, sig * ep * sqrtf(fabsf(d)));
    out[NSTEPS + n]     = fmaf(-sig, sig, 2.f * k * th);  // regs
    out[2 * NSTEPS + n] = d;                              // dts
    if ((n & 3) == 0)                                     // ODE closed-form chunk seed
        seeds[n >> 2] = th + (trace[1] - th) * __expf(-k * (e0.x - trace[0]));
}

// one step + derivative-product update (r stays ~0.05 > 0 on seed path; robust anyway)
#define GSTEP(dd, cc) { \
    float a   = fmaf(-k, (dd), 1.f); \
    float b   = kth * (dd); \
    float ar  = fabsf(r); \
    float sq  = sqrtf(ar); \
    float inv = (ar > 1e-30f) ? rsqrtf(ar) : 0.f; \
    float g   = fmaf(0.5f * (cc), copysignf(inv, r), a); \
    r = fmaf((cc), sq, fmaf(a, r, b)); \
    P *= g; }

#define FSTEP(dd, cc) { \
    float a = fmaf(-k, (dd), 1.f); \
    float b = kth * (dd); \
    rr = fmaf((cc), sqrtf(fabsf(rr)), fmaf(a, rr, b)); }

__device__ __forceinline__ void wave_scan_affine(float& A, float& B, int lane) {
#pragma unroll
    for (int d = 1; d < 64; d <<= 1) {
        float pA = __shfl_up(A, d, 64);
        float pB = __shfl_up(B, d, 64);
        if (lane >= d) { B = fmaf(A, pB, B); A *= pA; }
    }
}

// ---------------- K2: fused chunk + scan + final ----------------
__global__ void __launch_bounds__(K2T) fused_pass(
    const float2* __restrict__ dc, const float* __restrict__ seeds,
    const float* __restrict__ trace,
    const float* __restrict__ kp, const float* __restrict__ thp,
    float* __restrict__ out,
    float* __restrict__ gA, float* __restrict__ gB,
    unsigned int* __restrict__ cnt)
{
    __shared__ float wAs[16], wBs[16];
    __shared__ float sgA[K2B], sgB[K2B];
    const int tid = threadIdx.x, lane = tid & 63, wid = tid >> 6, bid = blockIdx.x;
    const int c = bid * K2T + tid;
    const float k = kp[0], th = thp[0], kth = k * th;
    const float4 q0 = ((const float4*)dc)[2 * c];       // (d0,c0,d1,c1)
    const float4 q1 = ((const float4*)dc)[2 * c + 1];   // (d2,c2,d3,c3)
    const float s = seeds[c];

    // forward 4 steps from seed, derivative product -> affine map x -> A*x+B
    float r = s, P = 1.f;
    GSTEP(q0.x, q0.y)
    GSTEP(q0.z, q0.w)
    GSTEP(q1.x, q1.y)
    GSTEP(q1.z, q1.w)
    float A = P, B = fmaf(-P, s, r);

    // block-level inclusive scan over 1024 thread maps
    float iA = A, iB = B;
    wave_scan_affine(iA, iB, lane);
    if (lane == 63) { wAs[wid] = iA; wBs[wid] = iB; }
    __syncthreads();
    if (wid == 0) {
        float aA = (lane < 16) ? wAs[lane] : 1.f;
        float aB = (lane < 16) ? wBs[lane] : 0.f;
        wave_scan_affine(aA, aB, lane);
        if (lane < 16) { wAs[lane] = aA; wBs[lane] = aB; }
    }
    __syncthreads();
    float weA = 1.f, weB = 0.f;
    if (wid > 0) { weA = wAs[wid - 1]; weB = wBs[wid - 1]; }
    float eA = __shfl_up(iA, 1, 64), eB = __shfl_up(iB, 1, 64);
    if (lane == 0) { eA = 1.f; eB = 0.f; }
    float Ate = eA * weA;                 // thread-exclusive prefix within block
    float Bte = fmaf(eA, weB, eB);

    // publish block aggregate (wAs[15],wBs[15]) + device-scope barrier
    if (tid == 0) {
        __hip_atomic_store(&gA[bid], wAs[15], __ATOMIC_RELAXED, __HIP_MEMORY_SCOPE_AGENT);
        __hip_atomic_store(&gB[bid], wBs[15], __ATOMIC_RELAXED, __HIP_MEMORY_SCOPE_AGENT);
        __hip_atomic_fetch_add(cnt, 1u, __ATOMIC_ACQ_REL, __HIP_MEMORY_SCOPE_AGENT);
        while (__hip_atomic_load(cnt, __ATOMIC_ACQUIRE, __HIP_MEMORY_SCOPE_AGENT) < K2B)
            __builtin_amdgcn_s_sleep(1);
    }
    __syncthreads();

    // every block redundantly scans the 256 block aggregates (AGENT-scope loads: no stale L1)
    if (tid < K2B) {
        sgA[tid] = __hip_atomic_load(&gA[tid], __ATOMIC_RELAXED, __HIP_MEMORY_SCOPE_AGENT);
        sgB[tid] = __hip_atomic_load(&gB[tid], __ATOMIC_RELAXED, __HIP_MEMORY_SCOPE_AGENT);
    }
    __syncthreads();
    for (int d = 1; d < K2B; d <<= 1) {
        float pA = 1.f, pB = 0.f;
        bool act = (tid < K2B) && (tid >= d);
        if (act) { pA = sgA[tid - d]; pB = sgB[tid - d]; }
        __syncthreads();
        if (act) { sgB[tid] = fmaf(sgA[tid], pB, sgB[tid]); sgA[tid] *= pA; }
        __syncthreads();
    }
    float beA = 1.f, beB = 0.f;
    if (bid > 0) { beA = sgA[bid - 1]; beB = sgB[bid - 1]; }

    // corrected start for this thread's 4 steps, replay, store
    float FA = Ate * beA;
    float FB = fmaf(Ate, beB, Bte);
    float rr = fmaf(FA, trace[1], FB);
    float4 ov;
    FSTEP(q0.x, q0.y) ov.x = rr;
    FSTEP(q0.z, q0.w) ov.y = rr;
    FSTEP(q1.x, q1.y) ov.z = rr;
    FSTEP(q1.z, q1.w) ov.w = rr;
    int nb = 4 * c;
    if (nb + 4 <= NSTEPS) {
        *(float4*)(out + nb) = ov;
    } else {                       // last thread only (step NSTEPS is pad)
        out[nb + 0] = ov.x;
        out[nb + 1] = ov.y;
        out[nb + 2] = ov.z;
    }
}

extern "C" void kernel_launch(void* const* d_in, const int* in_sizes, int n_in,
                              void* d_out, int out_size, void* d_ws, size_t ws_size,
                              hipStream_t stream)
{
    const float* trace = (const float*)d_in[0];
    const float* sW    = (const float*)d_in[1];
    const float* sb    = (const float*)d_in[2];
    const float* eW    = (const float*)d_in[3];
    const float* kp    = (const float*)d_in[4];
    const float* thp   = (const float*)d_in[5];
    float* out = (float*)d_out;

    float*        w     = (float*)d_ws;
    float2*       dc    = (float2*)w;                       // NPAD float2 = 8 MB
    float*        seeds = w + 2 * NPAD;                     // CHUNKS floats = 1 MB
    float*        gA    = seeds + CHUNKS;                   // K2B floats
    float*        gB    = gA + K2B;                         // K2B floats
    unsigned int* cnt   = (unsigned int*)(gB + K2B);        // 1 uint

    prep_kernel<<<NPAD / 256, 256, 0, stream>>>(trace, sW, sb, eW, kp, thp,
                                                dc, seeds, out, cnt);
    fused_pass<<<K2B, K2T, 0, stream>>>(dc, seeds, trace, kp, thp, out, gA, gB, cnt);
}